// Round 7
// baseline (115.013 us; speedup 1.0000x reference)
//
#include <hip/hip_runtime.h>
#include <hip/hip_bf16.h>
#include <math.h>

#define NA 250000
#define NG 64
#define NP 4096

#define SPAN 512                        // anchors per scan block
#define NB ((NA + SPAN - 1) / SPAN)     // 489 scan blocks
#define NBP 512                         // padded best-table width
#define RBLK (NP / 256)                 // 16 ROI blocks (appended to kA)

// ws float layout
#define OFF_TAB   0                             // [NG][NBP] per-(g,block) max
#define OFF_FORCE (OFF_TAB + NG * NBP)          // uint per anchor (dedupe flag)
#define OFF_ROI   (OFF_FORCE + NB * SPAN)       // 16 x 2 ROI block partials
#define OFF_ACC   (OFF_ROI + RBLK * 2)          // 4 floats: force-delta accum
#define OFF_SUM   (OFF_ACC + 4)                 // NB x 4 block partials (16B-aligned)

// ---------- shared math helpers ----------

// IoU and areas must be bitwise identical between kA (scan) and kF (force
// re-scan): contraction pinned off; identical inlined op sequences.
static __device__ __forceinline__ float area_of(float4 b) {
#pragma clang fp contract(off)
    return (b.z - b.x) * (b.w - b.y);
}

static __device__ __forceinline__ float iou_one(
    float gx0, float gy0, float gx1, float gy1, float ga,
    float ax0, float ay0, float ax1, float ay1, float aa)
{
#pragma clang fp contract(off)
    float ltx = fmaxf(gx0, ax0);
    float lty = fmaxf(gy0, ay0);
    float rbx = fminf(gx1, ax1);
    float rby = fminf(gy1, ay1);
    float w = fmaxf(rbx - ltx, 0.0f);
    float h = fmaxf(rby - lty, 0.0f);
    float inter = w * h;
    float uni = ga + aa - inter;
    return inter * __builtin_amdgcn_rcpf(uni);   // uni > 0 always
}

static __device__ __forceinline__ float smooth_l1_f(float d) {
    const float BETA = 1.0f / 9.0f;
    float ad = fabsf(d);
    return (ad < BETA) ? (0.5f * d * d / BETA) : (ad - 0.5f * BETA);
}

static __device__ __forceinline__ int matched_of(float maxv, int arg) {
    return (maxv < 0.3f) ? -1 : ((maxv < 0.7f) ? -2 : arg);
}

// RPN loss terms for one anchor given resolved `matched`. Accumulates.
static __device__ __forceinline__ void add_losses(
    int matched, const float4* __restrict__ gt,
    const float* __restrict__ gscore, const int* __restrict__ gconf,
    float4 av, float4 pd, float x,
    float& posf, float& negf, float& slpos, float& bces)
{
    int cl = matched < 0 ? 0 : matched;
    float4 Ac = gt[cl];                  // per-lane gather, 1KB L1-hot
    float score = gscore[cl];
    int conf = gconf[cl];
    float label = (matched >= 0) ? 1.0f : 0.0f;
    label = fminf(label, score);
    if (matched == -1) label = 0.0f;
    if (matched == -2) label = -1.0f;
    if (conf == 0 && matched >= 0) label = -1.0f;

    bool pos = (label >= 1.0f);
    bool neg = (label == 0.0f);
    bool sel = pos || neg;

    float aw = av.z - av.x, ah = av.w - av.y;
    float acx = av.x + 0.5f * aw, acy = av.y + 0.5f * ah;
    float gw = Ac.z - Ac.x, gh = Ac.w - Ac.y;
    float gcx = Ac.x + 0.5f * gw, gcy = Ac.y + 0.5f * gh;
    float t0 = (gcx - acx) / aw;
    float t1 = (gcy - acy) / ah;
    float t2 = __logf(gw / aw);
    float t3 = __logf(gh / ah);

    float sl = smooth_l1_f(pd.x - t0) + smooth_l1_f(pd.y - t1) +
               smooth_l1_f(pd.z - t2) + smooth_l1_f(pd.w - t3);

    float y = sel ? fminf(fmaxf(label, 0.0f), 1.0f) : 0.0f;
    float bce = fmaxf(x, 0.0f) - x * y + __logf(1.0f + __expf(-fabsf(x)));

    if (pos) { posf += 1.0f; slpos += sl; }
    if (neg) negf += 1.0f;
    if (sel) bces += bce;
}

// ---------- kernel A: scan + unforced losses (+ROI blocks) ----------
// blocks [0,NB): per-anchor max/argmax -> unforced losses -> block partials;
//               per-(g,block) max -> table; zero own force words.
// blocks [NB,NB+RBLK): ROI losses; zero table pad columns; r==0 zeroes acc.

__global__ __launch_bounds__(256) void kA(const float4* __restrict__ anchors,
                                          const float4* __restrict__ gt,
                                          const float* __restrict__ gscore,
                                          const int* __restrict__ gconf,
                                          const float* __restrict__ objness,
                                          const float4* __restrict__ pdel,
                                          const float* __restrict__ logits,
                                          const float* __restrict__ breg,
                                          const int* __restrict__ rlab,
                                          const float4* __restrict__ rtgt,
                                          const float* __restrict__ rsc,
                                          float* __restrict__ ws) {
    int t = threadIdx.x;
    int b = blockIdx.x;
    int lane = t & 63, w = t >> 6;

    if (b >= NB) {
        // ---- ROI block ----
        int r = b - NB;
        if (t < NBP - NB) {                  // zero table pad columns
#pragma unroll
            for (int row = 0; row < 4; row++)
                ws[OFF_TAB + (4 * r + row) * NBP + NB + t] = 0.0f;
        }
        if (r == 0 && t >= 32 && t < 36) ws[OFF_ACC + (t - 32)] = 0.0f;

        __shared__ float rbuf[4][2];
        int p = r * 256 + t;                 // 16*256 == NP
        float l0 = logits[2 * p], l1 = logits[2 * p + 1];
        float mx = fmaxf(l0, l1);
        float lse = mx + __logf(__expf(l0 - mx) + __expf(l1 - mx));
        float s = rsc[p];
        float clsl = -((1.0f - s) * (l0 - lse) + s * (l1 - lse));

        int lbl = rlab[p];
        int cl = lbl < 0 ? 0 : lbl;
        float4 bb = *(const float4*)(breg + 8 * p + 4 * cl);
        float4 tg = rtgt[p];
        float sl = smooth_l1_f(bb.x - tg.x) + smooth_l1_f(bb.y - tg.y) +
                   smooth_l1_f(bb.z - tg.z) + smooth_l1_f(bb.w - tg.w);
        float boxl = (lbl > 0) ? sl : 0.0f;

        for (int off = 32; off > 0; off >>= 1) {
            clsl += __shfl_down(clsl, off);
            boxl += __shfl_down(boxl, off);
        }
        if (lane == 0) { rbuf[w][0] = clsl; rbuf[w][1] = boxl; }
        __syncthreads();
        if (t == 0) {
            float s0 = 0.f, s1 = 0.f;
            for (int i = 0; i < 4; i++) { s0 += rbuf[i][0]; s1 += rbuf[i][1]; }
            ws[OFF_ROI + 2 * r] = s0;
            ws[OFF_ROI + 2 * r + 1] = s1;
        }
        return;
    }

    // ---- scan block ----
    unsigned* fw = (unsigned*)(ws + OFF_FORCE);
    fw[b * SPAN + t] = 0u;                   // zero own force words
    fw[b * SPAN + 256 + t] = 0u;

    int a0 = b * SPAN + t;
    int a1 = a0 + 256;
    bool ok0 = a0 < NA, ok1 = a1 < NA;
    float4 av0 = ok0 ? anchors[a0] : make_float4(0.f, 0.f, 0.f, 0.f);
    float4 av1 = ok1 ? anchors[a1] : make_float4(0.f, 0.f, 0.f, 0.f);
    float aa0 = area_of(av0);
    float aa1 = area_of(av1);
    float4 pd0 = ok0 ? pdel[a0] : make_float4(0.f, 0.f, 0.f, 0.f);
    float4 pd1 = ok1 ? pdel[a1] : make_float4(0.f, 0.f, 0.f, 0.f);
    float x0 = ok0 ? objness[a0] : 0.0f;
    float x1 = ok1 ? objness[a1] : 0.0f;

    float m[NG];
    float max0 = -1.0f, max1 = -1.0f;
    int arg0 = 0, arg1 = 0;
#pragma unroll
    for (int g = 0; g < NG; g++) {
        float4 G = gt[g];                    // uniform -> s_load
        float ga = area_of(G);
        float u0 = iou_one(G.x, G.y, G.z, G.w, ga, av0.x, av0.y, av0.z, av0.w, aa0);
        float u1 = iou_one(G.x, G.y, G.z, G.w, ga, av1.x, av1.y, av1.z, av1.w, aa1);
        if (u0 > max0) { max0 = u0; arg0 = g; }   // first-max == jnp.argmax
        if (u1 > max1) { max1 = u1; arg1 = g; }
        m[g] = fmaxf(fmaxf(u0, u1), 0.0f);        // NaN (fake anchors) -> 0
    }

    // per-(g,block) reduce -> table (kills m[] pressure before epilogue)
    __shared__ float sred[4][NG];
#pragma unroll
    for (int g = 0; g < NG; g++) {
        float mm = m[g];
        for (int off = 32; off > 0; off >>= 1)
            mm = fmaxf(mm, __shfl_down(mm, off));
        if (lane == 0) sred[w][g] = mm;
    }
    __syncthreads();
    if (t < NG) {
        float mm = fmaxf(fmaxf(sred[0][t], sred[1][t]),
                         fmaxf(sred[2][t], sred[3][t]));
        ws[OFF_TAB + t * NBP + b] = mm;      // plain store
    }

    // unforced epilogue
    float posf = 0.f, negf = 0.f, slpos = 0.f, bces = 0.f;
    if (ok0) add_losses(matched_of(max0, arg0), gt, gscore, gconf,
                        av0, pd0, x0, posf, negf, slpos, bces);
    if (ok1) add_losses(matched_of(max1, arg1), gt, gscore, gconf,
                        av1, pd1, x1, posf, negf, slpos, bces);

    __shared__ float rbuf[4][4];
    for (int off = 32; off > 0; off >>= 1) {
        posf  += __shfl_down(posf, off);
        negf  += __shfl_down(negf, off);
        slpos += __shfl_down(slpos, off);
        bces  += __shfl_down(bces, off);
    }
    if (lane == 0) { rbuf[w][0] = posf; rbuf[w][1] = negf; rbuf[w][2] = slpos; rbuf[w][3] = bces; }
    __syncthreads();
    if (t == 0) {
        float s0 = 0.f, s1 = 0.f, s2 = 0.f, s3 = 0.f;
        for (int i = 0; i < 4; i++) { s0 += rbuf[i][0]; s1 += rbuf[i][1]; s2 += rbuf[i][2]; s3 += rbuf[i][3]; }
        float* r = ws + OFF_SUM + 4 * b;
        r[0] = s0; r[1] = s1; r[2] = s2; r[3] = s3;   // plain stores
    }
}

// ---------- kernel F: force detection + loss deltas (64 blocks) ----------
// block g: reduce table row -> best_g; rescan only spans whose block max
// equals best_g; for each anchor achieving best_g (deduped via atomicExch),
// recompute its argmax and atomicAdd the (forced - unforced) loss delta.

__global__ __launch_bounds__(256) void kF(const float4* __restrict__ anchors,
                                          const float4* __restrict__ gt,
                                          const float* __restrict__ gscore,
                                          const int* __restrict__ gconf,
                                          const float* __restrict__ objness,
                                          const float4* __restrict__ pdel,
                                          float* __restrict__ ws) {
    __shared__ float srow[NBP];
    __shared__ float swm[4];
    __shared__ float sbest;
    __shared__ int scnt;
    __shared__ int slist[NBP];
    int t = threadIdx.x;
    int g = blockIdx.x;
    int lane = t & 63, w = t >> 6;

    const float* row = ws + OFF_TAB + g * NBP;
    float v0 = row[t], v1 = row[t + 256];
    srow[t] = v0; srow[t + 256] = v1;
    float mm = fmaxf(v0, v1);
    for (int off = 32; off > 0; off >>= 1)
        mm = fmaxf(mm, __shfl_down(mm, off));
    if (lane == 0) swm[w] = mm;
    if (t == 0) scnt = 0;
    __syncthreads();
    if (t == 0)
        sbest = fmaxf(fmaxf(swm[0], swm[1]), fmaxf(swm[2], swm[3]));
    __syncthreads();
    float best = sbest;

    if (srow[t] == best)       { int i = atomicAdd(&scnt, 1); slist[i] = t; }
    if (srow[t + 256] == best) { int i = atomicAdd(&scnt, 1); slist[i] = t + 256; }
    __syncthreads();

    float4 G = gt[g];                        // uniform -> s_load
    float ga = area_of(G);
    unsigned* fw = (unsigned*)(ws + OFF_FORCE);
    float* acc = ws + OFF_ACC;
    int cnt = scnt;
    for (int i = 0; i < cnt; i++) {
        int s = slist[i];
#pragma unroll
        for (int k = 0; k < 2; k++) {
            int a = s * SPAN + k * 256 + t;
            if (a >= NA) continue;
            float4 av = anchors[a];
            float aa = area_of(av);
            float u = iou_one(G.x, G.y, G.z, G.w, ga,
                              av.x, av.y, av.z, av.w, aa);
            if (u != best) continue;
            if (atomicExch(&fw[a], 1u) != 0u) continue;   // dedupe across GTs
            // recompute this anchor's argmax (bitwise-identical sequence)
            float maxv = -1.0f;
            int arg = 0;
            for (int j = 0; j < NG; j++) {
                float4 Gj = gt[j];
                float gaj = area_of(Gj);
                float uj = iou_one(Gj.x, Gj.y, Gj.z, Gj.w, gaj,
                                   av.x, av.y, av.z, av.w, aa);
                if (uj > maxv) { maxv = uj; arg = j; }
            }
            int mu = matched_of(maxv, arg);
            if (mu == arg) continue;          // force changes nothing
            float4 pd = pdel[a];
            float x = objness[a];
            float pu = 0.f, nu = 0.f, su = 0.f, bu = 0.f;
            float pf = 0.f, nf = 0.f, sf = 0.f, bf = 0.f;
            add_losses(mu, gt, gscore, gconf, av, pd, x, pu, nu, su, bu);
            add_losses(arg, gt, gscore, gconf, av, pd, x, pf, nf, sf, bf);
            atomicAdd(&acc[0], pf - pu);
            atomicAdd(&acc[1], nf - nu);
            atomicAdd(&acc[2], sf - su);
            atomicAdd(&acc[3], bf - bu);
        }
    }
}

// ---------- kernel C: final reduce (1 block, doubles) ----------

__global__ __launch_bounds__(256) void kC(const float* __restrict__ ws,
                                          float* __restrict__ out) {
    __shared__ double sred[4][6];
    int t = threadIdx.x;
    int lane = t & 63, w = t >> 6;
    double a0 = 0, a1 = 0, a2 = 0, a3 = 0, c0 = 0, c1 = 0;
    for (int r = t; r < NB; r += 256) {
        const float4 v = *(const float4*)(ws + OFF_SUM + 4 * r);
        a0 += v.x; a1 += v.y; a2 += v.z; a3 += v.w;
    }
    if (t < RBLK) {
        c0 = ws[OFF_ROI + 2 * t];
        c1 = ws[OFF_ROI + 2 * t + 1];
    }
    for (int off = 32; off > 0; off >>= 1) {
        a0 += __shfl_down(a0, off);
        a1 += __shfl_down(a1, off);
        a2 += __shfl_down(a2, off);
        a3 += __shfl_down(a3, off);
        c0 += __shfl_down(c0, off);
        c1 += __shfl_down(c1, off);
    }
    if (lane == 0) {
        sred[w][0] = a0; sred[w][1] = a1; sred[w][2] = a2;
        sred[w][3] = a3; sred[w][4] = c0; sred[w][5] = c1;
    }
    __syncthreads();
    if (t == 0) {
        double s[6] = {0, 0, 0, 0, 0, 0};
        for (int i = 0; i < 4; i++)
            for (int j = 0; j < 6; j++) s[j] += sred[i][j];
        // fold in force deltas (written by kF atomics, prior dispatch)
        s[0] += (double)ws[OFF_ACC + 0];
        s[1] += (double)ws[OFF_ACC + 1];
        s[2] += (double)ws[OFF_ACC + 2];
        s[3] += (double)ws[OFF_ACC + 3];
        double n = s[0] + s[1];
        out[0] = (float)(s[3] / n);            // objectness_loss
        out[1] = (float)(s[2] / n);            // rpn_box_loss
        out[2] = (float)(s[4] / (double)NP);   // classification_loss
        out[3] = (float)(s[5] / (double)NP);   // roi_box_loss
    }
}

extern "C" void kernel_launch(void* const* d_in, const int* in_sizes, int n_in,
                              void* d_out, int out_size, void* d_ws, size_t ws_size,
                              hipStream_t stream) {
    const float4* anchors = (const float4*)d_in[0];
    const float4* gt      = (const float4*)d_in[1];
    const float*  gscore  = (const float*)d_in[2];
    const int*    gconf   = (const int*)d_in[3];
    const float*  objness = (const float*)d_in[4];
    const float4* pdel    = (const float4*)d_in[5];
    const float*  clog    = (const float*)d_in[6];
    const float*  breg    = (const float*)d_in[7];
    const int*    rlab    = (const int*)d_in[8];
    const float4* rtgt    = (const float4*)d_in[9];
    const float*  rsc     = (const float*)d_in[10];

    float* ws = (float*)d_ws;
    float* out = (float*)d_out;

    kA<<<NB + RBLK, 256, 0, stream>>>(anchors, gt, gscore, gconf, objness, pdel,
                                      clog, breg, rlab, rtgt, rsc, ws);
    kF<<<NG, 256, 0, stream>>>(anchors, gt, gscore, gconf, objness, pdel, ws);
    kC<<<1, 256, 0, stream>>>(ws, out);
}